// Round 8
// baseline (4925.451 us; speedup 1.0000x reference)
//
#include <hip/hip_runtime.h>

// ---------------------------------------------------------------------------
// Problem constants (B=4, T=4096, D=1024, H=8, DK=1024, DV=2048, RANK=16,
// LOOPD=128, n_loops=4)
// ---------------------------------------------------------------------------
#define BB 4
#define TT 4096
#define DD 1024
#define HH 8
#define DKK 1024
#define DVV 2048
#define MR (BB*TT)          // 16384 rows
#define DKH 128
#define DVH 256
#define NLOOPS 4
#define LCH 128             // scan chunk length
#define NCH (TT/LCH)        // 32 chunks per batch
#define PADW 136            // LDS row stride (shorts) for scan kernels
#define NPROJ 7168          // q(1024) | k(1024) | lg(1024) | v(2048) | xg(2048)

// Total workspace need (bytes) — identical to rounds 3-6 (all passed).
// Sbf (64 MiB) aliases lgbuf (64 MiB) instead of growing the workspace:
// lg is consumed by c1 before c3 writes Sbf; c4 reads Sbf before the Wo
// GEMM overwrites the same memory as g2.
#define WS_NEED 662310912ull

// Static fallback workspace (module-load allocated; used when ws_size < WS_NEED)
__device__ __attribute__((aligned(256))) unsigned char g_ws[WS_NEED];

typedef __bf16 bf16x8 __attribute__((ext_vector_type(8)));
typedef float  f32x4  __attribute__((ext_vector_type(4)));

__device__ __forceinline__ unsigned short f2bfu(float f) {
    unsigned int u = __builtin_bit_cast(unsigned int, f);
    u += 0x7fffu + ((u >> 16) & 1u);
    return (unsigned short)(u >> 16);
}
__device__ __forceinline__ float bfu2f(unsigned short s) {
    unsigned int u = ((unsigned int)s) << 16;
    return __builtin_bit_cast(float, u);
}

__device__ __forceinline__ void gld_lds16(const void* g, void* l) {
    __builtin_amdgcn_global_load_lds(
        (__attribute__((address_space(1))) void*)const_cast<void*>(g),
        (__attribute__((address_space(3))) void*)l, 16, 0, 0);
}

// non-temporal stores: output streams bypass cache retention so they don't
// evict the GEMM's reused input panels from L2/L3 (proj FETCH was 10x inputs)
__device__ __forceinline__ void nts_u16(unsigned short* p, unsigned short v) {
    __builtin_nontemporal_store(v, p);
}
__device__ __forceinline__ void nts_f32(float* p, float v) {
    __builtin_nontemporal_store(v, p);
}

// ---------------------------------------------------------------------------
// Weight prep: fp32 [K][N] -> bf16 [N][K]  (B^T layout for the MFMA GEMM)
// ---------------------------------------------------------------------------
__global__ __launch_bounds__(256) void k_transpose_bf16(
    const float* __restrict__ in, unsigned short* __restrict__ out, int K, int N)
{
    __shared__ float tile[64][65];
    int k0 = blockIdx.y * 64, n0 = blockIdx.x * 64;
    int tx = threadIdx.x & 63, ty = threadIdx.x >> 6;
    #pragma unroll
    for (int r = 0; r < 64; r += 4)
        tile[ty + r][tx] = in[(size_t)(k0 + ty + r) * N + n0 + tx];
    __syncthreads();
    #pragma unroll
    for (int r = 0; r < 64; r += 4)
        out[(size_t)(n0 + ty + r) * K + k0 + tx] = f2bfu(tile[tx][ty + r]);
}

// e fp32 [MR][1024] -> bf16 into he[row][1024..2047]
__global__ __launch_bounds__(256) void k_conv_e(
    const float* __restrict__ e, unsigned short* __restrict__ he)
{
    size_t gid = (size_t)blockIdx.x * 256 + threadIdx.x;
    size_t b4 = gid * 4;
    size_t row = b4 >> 10; int col = (int)(b4 & 1023);
    float4 v = *(const float4*)&e[row * 1024 + col];
    *(ushort4*)&he[row * 2048 + 1024 + col] =
        make_ushort4(f2bfu(v.x), f2bfu(v.y), f2bfu(v.z), f2bfu(v.w));
}

// Combined injection weight: WinjT[n][0:1024]=injA[n][:] (diag zeroed,
// extracted), WinjT[n][1024:2048]=injB[n][:]
__global__ __launch_bounds__(256) void k_conv_injcomb(
    const float* __restrict__ injA, const float* __restrict__ injB,
    unsigned short* __restrict__ WinjT, float* __restrict__ diag)
{
    int idx = blockIdx.x * 256 + threadIdx.x;      // over 1024*1024
    int i = idx >> 10, j = idx & 1023;
    float va = injA[idx], vb = injB[idx];
    unsigned short ua;
    if (i == j) { diag[i] = va; ua = 0; }
    else        { ua = f2bfu(va); }
    WinjT[(size_t)i * 2048 + j] = ua;
    WinjT[(size_t)i * 2048 + 1024 + j] = f2bfu(vb);
}

// ---------------------------------------------------------------------------
// prep: h[:, :128] += loop_table[t]; xn = rmsnorm(h+e)*w -> bf16;
//       he[row][0:1024] = bf16(h)
// ---------------------------------------------------------------------------
__global__ __launch_bounds__(256) void k_prep(
    float* __restrict__ h, const float* __restrict__ e,
    const float* __restrict__ norm_w, const float* __restrict__ ltab,
    unsigned short* __restrict__ he, unsigned short* __restrict__ xn_bf)
{
    int row = blockIdx.x, tid = threadIdx.x;
    size_t base = (size_t)row * DD + tid * 4;
    float4 hv = *(float4*)&h[base];
    if (tid < 32) {
        float4 lv = *(const float4*)&ltab[tid * 4];
        hv.x += lv.x; hv.y += lv.y; hv.z += lv.z; hv.w += lv.w;
        *(float4*)&h[base] = hv;
    }
    float4 ev = *(const float4*)&e[base];
    float sx = hv.x + ev.x, sy = hv.y + ev.y, sz = hv.z + ev.z, sw = hv.w + ev.w;
    float partial = sx*sx + sy*sy + sz*sz + sw*sw;
    __shared__ float red[256];
    red[tid] = partial; __syncthreads();
    for (int st = 128; st > 0; st >>= 1) {
        if (tid < st) red[tid] += red[tid + st];
        __syncthreads();
    }
    float rms = rsqrtf(red[0] * (1.0f / DD) + 1e-6f);
    float4 wv = *(const float4*)&norm_w[tid * 4];
    *(ushort4*)&xn_bf[base] = make_ushort4(
        f2bfu(sx * rms * wv.x), f2bfu(sy * rms * wv.y),
        f2bfu(sz * rms * wv.z), f2bfu(sw * rms * wv.w));
    *(ushort4*)&he[(size_t)row * 2048 + tid * 4] =
        make_ushort4(f2bfu(hv.x), f2bfu(hv.y), f2bfu(hv.z), f2bfu(hv.w));
}

// ---------------------------------------------------------------------------
// Shared fragment/MFMA macros for the 256x256 8-wave GEMM core.
// Swizzle: byte a ^= ((a>>7)&7)<<4 within each 16K half (involution, 16B
// granule) — read-side XOR + pre-swizzled global source (linear LDS dest).
// ---------------------------------------------------------------------------
#define LD_AV(CB, MH) \
    _Pragma("unroll") \
    for (int i2 = 0; i2 < 4; ++i2) { \
        const char* rp = sm + (CB) + ((MH) * 16384) \
                       + ((wm * 64 + i2 * 16 + ln15) * 128); \
        av[i2][0] = *(const bf16x8*)(rp + xc0); \
        av[i2][1] = *(const bf16x8*)(rp + xc1); \
    }
#define LD_BV(CB, NH) \
    _Pragma("unroll") \
    for (int j2 = 0; j2 < 2; ++j2) { \
        const char* rp = sm + (CB) + 32768 + ((NH) * 16384) \
                       + ((wn * 32 + j2 * 16 + ln15) * 128); \
        bv[NH][j2][0] = *(const bf16x8*)(rp + xc0); \
        bv[NH][j2][1] = *(const bf16x8*)(rp + xc1); \
    }
#define MFMA_Q(MH, NH) \
    __builtin_amdgcn_s_setprio(1); \
    _Pragma("unroll") \
    for (int i2 = 0; i2 < 4; ++i2) \
        _Pragma("unroll") \
        for (int j2 = 0; j2 < 2; ++j2) { \
            acc[(MH)*4+i2][(NH)*2+j2] = __builtin_amdgcn_mfma_f32_16x16x32_bf16( \
                av[i2][0], bv[NH][j2][0], acc[(MH)*4+i2][(NH)*2+j2], 0, 0, 0); \
            acc[(MH)*4+i2][(NH)*2+j2] = __builtin_amdgcn_mfma_f32_16x16x32_bf16( \
                av[i2][1], bv[NH][j2][1], acc[(MH)*4+i2][(NH)*2+j2], 0, 0, 0); \
        } \
    __builtin_amdgcn_s_setprio(0);

// ---------------------------------------------------------------------------
// Single-tile 256x256 8-wave GEMM core, fragment-reuse + read-ahead.
// (Round-3/4 verified structure: epilogue strictly AFTER the loop — r6 showed
// interleaving stores with the peel breaks vmcnt induction (stores count in
// vmcnt on CDNA) and amplifies writes.)
// Per K-tile:
//   P0: stage A-h0(next); vmcnt(4); bar; read av0+bv0+bv1 [16]; MFMA(0,0)
//   P1: stage B-h0(next);                                       MFMA(0,1)
//   P2: stage B-h1(next); vmcnt(6); bar; read av1         [8];  MFMA(1,1)
//   P3: stage A-h1(next);                                       MFMA(1,0)
// vmcnt induction (units of 2 loads): entering P0 = 8 outstanding
// [A0,B0,B1,A1](cur); +stage=10; vmcnt(4) drains A0,B0,B1(cur);
// P2: 8, vmcnt(6) drains A1(cur). Peel: 8 -> vmcnt(2) -> vmcnt(0).
// ---------------------------------------------------------------------------
template<int KB>   // K dimension in BYTES (= 2*K elements)
__device__ __forceinline__ void gemm8_core(
    const char* __restrict__ Ab, const char* __restrict__ Bb,
    int bm, int bn, char* sm, f32x4 (&acc)[8][4])
{
    constexpr int NKT = KB / 128;      // number of 64-element K-tiles
    const int tid = threadIdx.x;
    const int lane = tid & 63;
    const int wave = tid >> 6;
    const int wm = wave >> 2, wn = wave & 3;
    const int ln15 = lane & 15, q4 = lane >> 4;
    const int xorv = (ln15 & 7) << 4;
    const int xc0 = (q4 * 16) ^ xorv;
    const int xc1 = (64 + q4 * 16) ^ xorv;

    const int L0 = tid * 16;
    const int L1 = 8192 + tid * 16;
    const int lin0 = L0 ^ (((L0 >> 7) & 7) << 4);
    const int lin1 = L1 ^ (((L1 >> 7) & 7) << 4);
    const int sr0 = lin0 >> 7, sc0 = lin0 & 127;
    const int sr1 = lin1 >> 7, sc1 = lin1 & 127;

    bf16x8 av[4][2];
    bf16x8 bv[2][2][2];

    auto STAGE = [&](const char* gb, int row0, int kcol, int region) {
        gld_lds16(gb + (size_t)(row0 + sr0) * KB + (kcol + sc0), sm + region + L0);
        gld_lds16(gb + (size_t)(row0 + sr1) * KB + (kcol + sc1), sm + region + L1);
    };

    STAGE(Ab, bm,       0, 0);
    STAGE(Bb, bn,       0, 32768);
    STAGE(Bb, bn + 128, 0, 49152);
    STAGE(Ab, bm + 128, 0, 16384);

    #pragma unroll 2
    for (int kt = 0; kt < NKT - 1; ++kt) {
        const int cb = (kt & 1) << 16;
        const int sb = cb ^ 65536;
        const int kcol = (kt + 1) * 128;
        STAGE(Ab, bm, kcol, sb);
        asm volatile("s_waitcnt vmcnt(4)" ::: "memory");
        __builtin_amdgcn_s_barrier();
        LD_AV(cb, 0)
        LD_BV(cb, 0)
        LD_BV(cb, 1)
        MFMA_Q(0, 0)
        STAGE(Bb, bn, kcol, sb + 32768);
        MFMA_Q(0, 1)
        STAGE(Bb, bn + 128, kcol, sb + 49152);
        asm volatile("s_waitcnt vmcnt(6)" ::: "memory");
        __builtin_amdgcn_s_barrier();
        LD_AV(cb, 1)
        MFMA_Q(1, 1)
        STAGE(Ab, bm + 128, kcol, sb + 16384);
        MFMA_Q(1, 0)
    }
    {   // peeled last K-tile: drain 2 -> 0
        const int cb = ((NKT - 1) & 1) << 16;
        asm volatile("s_waitcnt vmcnt(2)" ::: "memory");
        __builtin_amdgcn_s_barrier();
        LD_AV(cb, 0)
        LD_BV(cb, 0)
        LD_BV(cb, 1)
        MFMA_Q(0, 0)
        MFMA_Q(0, 1)
        asm volatile("s_waitcnt vmcnt(0)" ::: "memory");
        __builtin_amdgcn_s_barrier();
        LD_AV(cb, 1)
        MFMA_Q(1, 1)
        MFMA_Q(1, 0)
    }
}

// ---------------------------------------------------------------------------
// Fused 5-way projection GEMM on the core (grid 1792, XCD swizzle).
// N-segments all 256-aligned: q[0,1024) k[1024,2048) lg[2048,3072)
// v[3072,5120) xg[5120,7168).
// Outputs stored NON-TEMPORAL: the 268MB output stream was evicting the
// 48MB reused input panels from L3 (FETCH_SIZE 488MB = 10x inputs).
// ---------------------------------------------------------------------------
__global__ __launch_bounds__(512, 2) void k_gemm_proj8(
    const unsigned short* __restrict__ A, const unsigned short* __restrict__ Bt,
    unsigned short* __restrict__ qout, unsigned short* __restrict__ kout,
    float* __restrict__ lgout, unsigned short* __restrict__ vout,
    unsigned short* __restrict__ xgout, float qscale)
{
    extern __shared__ char sm[];
    // bijective XCD swizzle: nwg=1792, 1792/8=224
    int bid = blockIdx.x;
    int nb = (bid & 7) * 224 + (bid >> 3);
    int bm = (nb / 28) * 256, bn = (nb % 28) * 256;

    f32x4 acc[8][4];
    #pragma unroll
    for (int i = 0; i < 8; ++i)
        #pragma unroll
        for (int j = 0; j < 4; ++j) { f32x4 z = {0,0,0,0}; acc[i][j] = z; }

    gemm8_core<2048>((const char*)A, (const char*)Bt, bm, bn, sm, acc);

    const int tid = threadIdx.x, lane = tid & 63, wave = tid >> 6;
    const int wm = wave >> 2, wn = wave & 3;
    const int ln15 = lane & 15, q4 = lane >> 4;

    if (bn >= 2048 && bn < 3072) {
        int cb = bn - 2048;
        #pragma unroll
        for (int fm = 0; fm < 8; ++fm) {
            int mh = fm >> 2, i2 = fm & 3;
            int rowb = bm + mh * 128 + wm * 64 + i2 * 16 + q4 * 4;
            #pragma unroll
            for (int fn = 0; fn < 4; ++fn) {
                int nh = fn >> 1, j2 = fn & 1;
                int col = cb + nh * 128 + wn * 32 + j2 * 16 + ln15;
                #pragma unroll
                for (int r = 0; r < 4; ++r) {
                    float v = acc[fm][fn][r];
                    v = (fminf(v, 0.f) - log1pf(expf(-fabsf(v)))) * 0.0625f;
                    nts_f32(&lgout[(size_t)(rowb + r) * 1024 + col], v);
                }
            }
        }
    } else {
        unsigned short* obuf; int stride, cbc;
        float scale = 1.f;
        if (bn < 1024)      { obuf = qout;  stride = 1024; cbc = bn;        scale = qscale; }
        else if (bn < 2048) { obuf = kout;  stride = 1024; cbc = bn - 1024; }
        else if (bn < 5120) { obuf = vout;  stride = 2048; cbc = bn - 3072; }
        else                { obuf = xgout; stride = 2048; cbc = bn - 5120; }
        #pragma unroll
        for (int fm = 0; fm < 8; ++fm) {
            int mh = fm >> 2, i2 = fm & 3;
            int rowb = bm + mh * 128 + wm * 64 + i2 * 16 + q4 * 4;
            #pragma unroll
            for (int fn = 0; fn < 4; ++fn) {
                int nh = fn >> 1, j2 = fn & 1;
                int col = cbc + nh * 128 + wn * 32 + j2 * 16 + ln15;
                #pragma unroll
                for (int r = 0; r < 4; ++r)
                    nts_u16(&obuf[(size_t)(rowb + r) * stride + col],
                            f2bfu(acc[fm][fn][r] * scale));
            }
        }
    }
}

// fp32-output GEMM (Wo / injection) on the core.
// HASADD: += addend[oi]; HASDIAG: += hsrc[oi]*diag[col] (in-place-safe).
// Outputs kept temporal: h/g2 are re-read immediately by the next kernel.
template<int HASADD, int HASDIAG, int KB>
__global__ __launch_bounds__(512, 2) void k_gemm8_f32(
    const unsigned short* __restrict__ A, const unsigned short* __restrict__ Bt,
    float* __restrict__ out, const float* __restrict__ addend,
    const float* __restrict__ hsrc, const float* __restrict__ diag, int N)
{
    extern __shared__ char sm[];
    int bid = blockIdx.x;
    int cpx = gridDim.x >> 3;                  // nwg % 8 == 0
    int nb = (bid & 7) * cpx + (bid >> 3);
    int nbn = N >> 8;
    int bm = (nb / nbn) * 256, bn = (nb % nbn) * 256;

    f32x4 acc[8][4];
    #pragma unroll
    for (int i = 0; i < 8; ++i)
        #pragma unroll
        for (int j = 0; j < 4; ++j) { f32x4 z = {0,0,0,0}; acc[i][j] = z; }

    gemm8_core<KB>((const char*)A, (const char*)Bt, bm, bn, sm, acc);

    const int tid = threadIdx.x, lane = tid & 63, wave = tid >> 6;
    const int wm = wave >> 2, wn = wave & 3;
    const int ln15 = lane & 15, q4 = lane >> 4;

    #pragma unroll
    for (int fm = 0; fm < 8; ++fm) {
        int mh = fm >> 2, i2 = fm & 3;
        int rowb = bm + mh * 128 + wm * 64 + i2 * 16 + q4 * 4;
        #pragma unroll
        for (int fn = 0; fn < 4; ++fn) {
            int nh = fn >> 1, j2 = fn & 1;
            int col = bn + nh * 128 + wn * 32 + j2 * 16 + ln15;
            float dg = 0.f;
            if (HASDIAG) dg = diag[col];
            #pragma unroll
            for (int r = 0; r < 4; ++r) {
                size_t oi = (size_t)(rowb + r) * N + col;
                float v = acc[fm][fn][r];
                if (HASDIAG) v += hsrc[oi] * dg;
                if (HASADD)  v += addend[oi];
                out[oi] = v;
            }
        }
    }
}

#undef LD_AV
#undef LD_BV
#undef MFMA_Q

// ---------------------------------------------------------------------------
// Chunked GLA scan, phase C1: per (chunk, bh), per channel i:
//   c_t = cumsum(lg); q <- q*exp(c_t); k <- k*exp(-c_t); dLe = exp(c_L)
// 256 threads = 2 bh per block.
// ---------------------------------------------------------------------------
__global__ __launch_bounds__(256) void k_c1(
    const float* __restrict__ lg, unsigned short* __restrict__ q,
    unsigned short* __restrict__ kk, float* __restrict__ dLe)
{
    int chunk = blockIdx.x;
    int bh = blockIdx.y * 2 + (threadIdx.x >> 7);
    int b = bh >> 3, h = bh & 7;
    int i = threadIdx.x & 127;
    size_t r0 = (size_t)b * TT + (size_t)chunk * LCH;
    float c = 0.f, e = 1.f;
    for (int t = 0; t < LCH; ++t) {
        size_t off = (r0 + t) * DKK + h * DKH + i;
        c += lg[off];
        e = __expf(c);
        float ei = __expf(-c);
        q[off] = f2bfu(bfu2f(q[off]) * e);
        kk[off] = f2bfu(bfu2f(kk[off]) * ei);
    }
    dLe[((size_t)chunk * 32 + bh) * DKH + i] = e;
}

// ---------------------------------------------------------------------------
// C2: per (chunk, bh): P = causal(Q~ K~^T);  O_intra = P V -> ob (bf16);
//     U = K~^T V -> fp32.  Dynamic LDS: 4 * 128*PADW shorts = 139264 B.
// 512 threads (8 waves), 2(wm) x 4(wn) wave grid over each 128-wide panel.
// ---------------------------------------------------------------------------
__global__ __launch_bounds__(512, 1) void k_c2(
    const unsigned short* __restrict__ q, const unsigned short* __restrict__ kk,
    const unsigned short* __restrict__ v, unsigned short* __restrict__ ob,
    float* __restrict__ U)
{
    extern __shared__ unsigned short smd[];
    unsigned short* lQ  = smd;                 // [t][i], later P [t][s]
    unsigned short* lK  = smd + LCH * PADW;    // [s][i]
    unsigned short* lKT = smd + 2 * LCH * PADW;// [i][s]
    unsigned short* lVT = smd + 3 * LCH * PADW;// [j][s] (one 128-wide j panel)

    int chunk = blockIdx.x, bh = blockIdx.y;
    int b = bh >> 3, h = bh & 7;
    int tid = threadIdx.x, lane = tid & 63, wave = tid >> 6;
    int wm = wave >> 2, wn = wave & 3;
    int quad = lane >> 4, mr = lane & 15;
    size_t r0 = (size_t)b * TT + (size_t)chunk * LCH;

    #pragma unroll
    for (int ps = 0; ps < 4; ++ps) {
        int idx = ps * 512 + tid;
        int row = idx >> 4, c8 = (idx & 15) * 8;
        size_t g = (r0 + row) * DKK + h * DKH + c8;
        *(int4*)&lQ[row * PADW + c8] = *(const int4*)&q[g];
        union { int4 w; unsigned short u[8]; } tmp;
        tmp.w = *(const int4*)&kk[g];
        *(int4*)&lK[row * PADW + c8] = tmp.w;
        #pragma unroll
        for (int u2 = 0; u2 < 8; ++u2)
            lKT[(c8 + u2) * PADW + row] = tmp.u[u2];
    }
    __syncthreads();

    f32x4 pa[4][2];
    #pragma unroll
    for (int i = 0; i < 4; ++i)
        #pragma unroll
        for (int j = 0; j < 2; ++j) { f32x4 z = {0,0,0,0}; pa[i][j] = z; }
    for (int k0 = 0; k0 < DKH; k0 += 32) {
        bf16x8 av[4], bvv[2];
        #pragma unroll
        for (int t2 = 0; t2 < 4; ++t2)
            av[t2] = *(const bf16x8*)&lQ[(wm * 64 + t2 * 16 + mr) * PADW + k0 + quad * 8];
        #pragma unroll
        for (int tn = 0; tn < 2; ++tn)
            bvv[tn] = *(const bf16x8*)&lK[(wn * 32 + tn * 16 + mr) * PADW + k0 + quad * 8];
        #pragma unroll
        for (int tm = 0; tm < 4; ++tm)
            #pragma unroll
            for (int tn = 0; tn < 2; ++tn)
                pa[tm][tn] = __builtin_amdgcn_mfma_f32_16x16x32_bf16(
                    av[tm], bvv[tn], pa[tm][tn], 0, 0, 0);
    }
    __syncthreads();

    #pragma unroll
    for (int tm = 0; tm < 4; ++tm)
        #pragma unroll
        for (int tn = 0; tn < 2; ++tn)
            #pragma unroll
            for (int r = 0; r < 4; ++r) {
                int trow = wm * 64 + tm * 16 + quad * 4 + r;
                int scol = wn * 32 + tn * 16 + mr;
                float pv = (trow >= scol) ? pa[tm][tn][r] : 0.f;
                lQ[trow * PADW + scol] = f2bfu(pv);
            }
    #pragma unroll
    for (int ps = 0; ps < 4; ++ps) {
        int idx = ps * 512 + tid;
        int s = idx >> 4, j8 = (idx & 15) * 8;
        size_t g = (r0 + s) * DVV + h * DVH + j8;   // panel 0
        union { int4 w; unsigned short u[8]; } tmp;
        tmp.w = *(const int4*)&v[g];
        #pragma unroll
        for (int u2 = 0; u2 < 8; ++u2)
            lVT[(j8 + u2) * PADW + s] = tmp.u[u2];
    }
    __syncthreads();

    #pragma unroll 1
    for (int panel = 0; panel < 2; ++panel) {
        f32x4 oa[4][2], ua[4][2];
        #pragma unroll
        for (int i = 0; i < 4; ++i)
            #pragma unroll
            for (int j = 0; j < 2; ++j) { f32x4 z = {0,0,0,0}; oa[i][j] = z; ua[i][j] = z; }
        for (int k0 = 0; k0 < LCH; k0 += 32) {
            bf16x8 pv[4], kt[4], vb[2];
            #pragma unroll
            for (int t2 = 0; t2 < 4; ++t2) {
                pv[t2] = *(const bf16x8*)&lQ [(wm * 64 + t2 * 16 + mr) * PADW + k0 + quad * 8];
                kt[t2] = *(const bf16x8*)&lKT[(wm * 64 + t2 * 16 + mr) * PADW + k0 + quad * 8];
            }
            #pragma unroll
            for (int tn = 0; tn < 2; ++tn)
                vb[tn] = *(const bf16x8*)&lVT[(wn * 32 + tn * 16 + mr) * PADW + k0 + quad * 8];
            #pragma unroll
            for (int tm = 0; tm < 4; ++tm)
                #pragma unroll
                for (int tn = 0; tn < 2; ++tn) {
                    oa[tm][tn] = __builtin_amdgcn_mfma_f32_16x16x32_bf16(
                        pv[tm], vb[tn], oa[tm][tn], 0, 0, 0);
                    ua[tm][tn] = __builtin_amdgcn_mfma_f32_16x16x32_bf16(
                        kt[tm], vb[tn], ua[tm][tn], 0, 0, 0);
                }
        }
        #pragma unroll
        for (int tm = 0; tm < 4; ++tm)
            #pragma unroll
            for (int tn = 0; tn < 2; ++tn)
                #pragma unroll
                for (int r = 0; r < 4; ++r) {
                    int m_ = wm * 64 + tm * 16 + quad * 4 + r;
                    int j_ = panel * 128 + wn * 32 + tn * 16 + mr;
                    ob[(r0 + m_) * DVV + h * DVH + j_] = f2bfu(oa[tm][tn][r]);
                    U[(((size_t)chunk * 32 + bh) * DKH + m_) * DVH + j_] = ua[tm][tn][r];
                }
        __syncthreads();
        if (panel == 0) {
            #pragma unroll
            for (int ps = 0; ps < 4; ++ps) {
                int idx = ps * 512 + tid;
                int s = idx >> 4, j8 = (idx & 15) * 8;
                size_t g = (r0 + s) * DVV + h * DVH + 128 + j8;   // panel 1
                union { int4 w; unsigned short u[8]; } tmp;
                tmp.w = *(const int4*)&v[g];
                #pragma unroll
                for (int u2 = 0; u2 < 8; ++u2)
                    lVT[(j8 + u2) * PADW + s] = tmp.u[u2];
            }
            __syncthreads();
        }
    }
}

// ---------------------------------------------------------------------------
// C3: sequential inter-chunk combine.  Reads U (fp32, from c2); writes the
// PRE-update state S_c as bf16 into Sbf (c4 converts to bf16 for MFMA anyway
// — same rounding, applied earlier; halves c3-write + c4-read traffic).
// Sbf aliases lgbuf (lg already consumed by c1; Wo GEMM overwrites later).
// ---------------------------------------------------------------------------
__global__ __launch_bounds__(256) void k_c3(
    const float* __restrict__ U, const float* __restrict__ dLe,
    unsigned short* __restrict__ Sbf)
{
    int gid = blockIdx.x * 256 + threadIdx.x;   // 262144 threads
    int bh = gid >> 13;
    int rem = gid & 8191;
    int i = rem >> 6, j4 = rem & 63;
    float4 S = make_float4(0.f, 0.f, 0.f, 0.f);
    for (int c = 0; c < NCH; ++c) {
        size_t off = (((size_t)c * 32 + bh) * DKH + i) * DVH + j4 * 4;
        float4 u = *(const float4*)&U[off];
        *(ushort4*)&Sbf[off] = make_ushort4(
            f2bfu(S.x), f2bfu(S.y), f2bfu(S.z), f2bfu(S.w));
        float d = dLe[((size_t)c * 32 + bh) * DKH + i];
        S.x = d * (S.x + u.x); S.y = d * (S.y + u.y);
        S.z = d * (S.z + u.z); S.w = d * (S.w + u.w);
    }
}

// ---------------------------------------------------------------------------
// C4: ob = (ob_intra + Q~ @ S_c) * silu(xg)   (gate fused), S in bf16.
// Dynamic LDS: 2 * 128*PADW shorts = 69632 B.
// ---------------------------------------------------------------------------
__global__ __launch_bounds__(256, 1) void k_c4(
    const unsigned short* __restrict__ q, const unsigned short* __restrict__ Sbf,
    unsigned short* __restrict__ ob, const unsigned short* __restrict__ xg)
{
    extern __shared__ unsigned short smd[];
    unsigned short* lQ  = smd;               // [t][i]
    unsigned short* lST = smd + LCH * PADW;  // [j][i]

    int chunk = blockIdx.x, bh = blockIdx.y;
    int b = bh >> 3, h = bh & 7;
    int tid = threadIdx.x, lane = tid & 63, wave = tid >> 6;
    int wm = wave >> 1, wn = wave & 1;
    int quad = lane >> 4, mr = lane & 15;
    size_t r0 = (size_t)b * TT + (size_t)chunk * LCH;
    size_t sbase = ((size_t)chunk * 32 + bh) * DKH * DVH;

    #pragma unroll
    for (int ps = 0; ps < 8; ++ps) {
        int idx = ps * 256 + tid;
        int row = idx >> 4, c8 = (idx & 15) * 8;
        size_t g = (r0 + row) * DKK + h * DKH + c8;
        *(int4*)&lQ[row * PADW + c8] = *(const int4*)&q[g];
    }

    #pragma unroll 1
    for (int panel = 0; panel < 2; ++panel) {
        __syncthreads();
        #pragma unroll
        for (int ps = 0; ps < 8; ++ps) {
            int idx = ps * 256 + tid;
            int i = idx >> 4, j8 = (idx & 15) * 8;
            union { int4 w; unsigned short u[8]; } t8;
            t8.w = *(const int4*)&Sbf[sbase + (size_t)i * DVH + panel * 128 + j8];
            #pragma unroll
            for (int u2 = 0; u2 < 8; ++u2)
                lST[(j8 + u2) * PADW + i] = t8.u[u2];
        }
        __syncthreads();

        f32x4 oa[4][4];
        #pragma unroll
        for (int i = 0; i < 4; ++i)
            #pragma unroll
            for (int j = 0; j < 4; ++j) { f32x4 z = {0,0,0,0}; oa[i][j] = z; }
        for (int k0 = 0; k0 < DKH; k0 += 32) {
            bf16x8 av[4], bvv[4];
            #pragma unroll
            for (int t2 = 0; t2 < 4; ++t2) {
                av[t2] = *(const bf16x8*)&lQ [(wm * 64 + t2 * 16 + mr) * PADW + k0 + quad * 8];
                bvv[t2] = *(const bf16x8*)&lST[(wn * 64 + t2 * 16 + mr) * PADW + k0 + quad * 8];
            }
            #pragma unroll
            for (int tm = 0; tm < 4; ++tm)
                #pragma unroll
                for (int tn = 0; tn < 4; ++tn)
                    oa[tm][tn] = __builtin_amdgcn_mfma_f32_16x16x32_bf16(
                        av[tm], bvv[tn], oa[tm][tn], 0, 0, 0);
        }
        #pragma unroll
        for (int tm = 0; tm < 4; ++tm)
            #pragma unroll
            for (int tn = 0; tn < 4; ++tn)
                #pragma unroll
                for (int r = 0; r < 4; ++r) {
                    int t_ = wm * 64 + tm * 16 + quad * 4 + r;
                    int j_ = panel * 128 + wn * 64 + tn * 16 + mr;
                    size_t oi = (r0 + t_) * DVV + h * DVH + j_;
                    float ov = bfu2f(ob[oi]) + oa[tm][tn][r];
                    float xf = bfu2f(xg[oi]);
                    ob[oi] = f2bfu(ov * xf / (1.f + expf(-xf)));
                }
    }
}

// ---------------------------------------------------------------------------
// LoRA rank-16, fp32
// ---------------------------------------------------------------------------
__global__ __launch_bounds__(256) void k_lora1(
    const float* __restrict__ G, const float* __restrict__ A, float* __restrict__ tmp)
{
    int row = blockIdx.x * 4 + (threadIdx.x >> 6);
    int lane = threadIdx.x & 63;
    float acc[16];
    #pragma unroll
    for (int r = 0; r < 16; ++r) acc[r] = 0.f;
    const float* grow = G + (size_t)row * DD;
    for (int k2 = lane; k2 < DD; k2 += 64) {
        float g = grow[k2];
        const float4* ar = (const float4*)(A + k2 * 16);
        float4 a0 = ar[0], a1 = ar[1], a2 = ar[2], a3 = ar[3];
        acc[0] = fmaf(g, a0.x, acc[0]);  acc[1] = fmaf(g, a0.y, acc[1]);
        acc[2] = fmaf(g, a0.z, acc[2]);  acc[3] = fmaf(g, a0.w, acc[3]);
        acc[4] = fmaf(g, a1.x, acc[4]);  acc[5] = fmaf(g, a1.y, acc[5]);
        acc[6] = fmaf(g, a1.z, acc[6]);  acc[7] = fmaf(g, a1.w, acc[7]);
        acc[8] = fmaf(g, a2.x, acc[8]);  acc[9] = fmaf(g, a2.y, acc[9]);
        acc[10] = fmaf(g, a2.z, acc[10]); acc[11] = fmaf(g, a2.w, acc[11]);
        acc[12] = fmaf(g, a3.x, acc[12]); acc[13] = fmaf(g, a3.y, acc[13]);
        acc[14] = fmaf(g, a3.z, acc[14]); acc[15] = fmaf(g, a3.w, acc[15]);
    }
    #pragma unroll
    for (int off = 32; off >= 1; off >>= 1)
        #pragma unroll
        for (int r = 0; r < 16; ++r) acc[r] += __shfl_xor(acc[r], off);
    if (lane == 0) {
        #pragma unroll
        for (int r = 0; r < 16; ++r) tmp[(size_t)row * 16 + r] = acc[r];
    }
}

__global__ __launch_bounds__(256) void k_lora2(
    float* __restrict__ G, const float* __restrict__ tmp, const float* __restrict__ Bm)
{
    int row = blockIdx.x, tid = threadIdx.x;
    __shared__ float t16[16];
    if (tid < 16) t16[tid] = tmp[(size_t)row * 16 + tid];
    __syncthreads();
    size_t base = (size_t)row * DD + tid * 4;
    float4 acc = *(float4*)&G[base];
    #pragma unroll
    for (int r = 0; r < 16; ++r) {
        float tv = t16[r];
        float4 bv = *(const float4*)&Bm[r * DD + tid * 4];
        acc.x = fmaf(tv, bv.x, acc.x); acc.y = fmaf(tv, bv.y, acc.y);
        acc.z = fmaf(tv, bv.z, acc.z); acc.w = fmaf(tv, bv.w, acc.w);
    }
    *(float4*)&G[base] = acc;
}

// ---------------------------------------------------------------------------
// ACT halting (race-free via LDS staging)
// ---------------------------------------------------------------------------
__global__ __launch_bounds__(256) void k_act(
    const float* __restrict__ h, const float* __restrict__ act_w,
    const float* __restrict__ act_b, float* __restrict__ out,
    float* __restrict__ cum, int* __restrict__ halted)
{
    int row = blockIdx.x, tid = threadIdx.x;
    size_t base = (size_t)row * DD + tid * 4;
    float4 hv = *(const float4*)&h[base];
    float4 wv = *(const float4*)&act_w[tid * 4];
    float partial = hv.x*wv.x + hv.y*wv.y + hv.z*wv.z + hv.w*wv.w;
    __shared__ float red[256];
    __shared__ float s_cm;
    __shared__ int s_hl;
    if (tid == 0) { s_cm = cum[row]; s_hl = halted[row]; }
    red[tid] = partial; __syncthreads();
    for (int st = 128; st > 0; st >>= 1) {
        if (tid < st) red[tid] += red[tid + st];
        __syncthreads();
    }
    float p = 1.f / (1.f + expf(-(red[0] + act_b[0])));
    float cm = s_cm;
    int hl = s_hl;
    float p_eff = hl ? 0.f : p;
    float ncum = cm + p_eff;
    int newly = (!hl) && (ncum >= 0.99f);
    float w = newly ? (1.f - cm) : p_eff;
    float4 ho = *(float4*)&out[base];
    ho.x += w * hv.x; ho.y += w * hv.y; ho.z += w * hv.z; ho.w += w * hv.w;
    *(float4*)&out[base] = ho;
    if (tid == 0) { cum[row] = ncum; halted[row] = hl | newly; }
}

__global__ __launch_bounds__(256) void k_final(
    float* __restrict__ io, const float* __restrict__ w)
{
    int row = blockIdx.x, tid = threadIdx.x;
    size_t base = (size_t)row * DD + tid * 4;
    float4 hv = *(const float4*)&io[base];
    float partial = hv.x*hv.x + hv.y*hv.y + hv.z*hv.z + hv.w*hv.w;
    __shared__ float red[256];
    red[tid] = partial; __syncthreads();
    for (int st = 128; st > 0; st >>= 1) {
        if (tid < st) red[tid] += red[tid + st];
        __syncthreads();
    }
    float rms = rsqrtf(red[0] * (1.0f / DD) + 1e-6f);
    float4 wv = *(const float4*)&w[tid * 4];
    float4 o = make_float4(hv.x*rms*wv.x, hv.y*rms*wv.y, hv.z*rms*wv.z, hv.w*rms*wv.w);
    *(float4*)&io[base] = o;
}

// ---------------------------------------------------------------------------
extern "C" void kernel_launch(void* const* d_in, const int* in_sizes, int n_in,
                              void* d_out, int out_size, void* d_ws, size_t ws_size,
                              hipStream_t stream)
{
    const float* in_h       = (const float*)d_in[0];
    const float* in_e       = (const float*)d_in[1];
    const float* norm_w     = (const float*)d_in[2];
    const float* out_norm_w = (const float*)d_in[3];
    const float* Wq   = (const float*)d_in[4];
    const float* Wk   = (const float*)d_in[5];
    const float* Wv   = (const float*)d_in[6];
    const float* Wgk  = (const float*)d_in[7];
    const float* Wg   = (const float*)d_in[8];
    const float* Wo   = (const float*)d_in[9];
    const float* lora_A = (const float*)d_in[10];
    const float* lora_B = (const float*)d_in[11];
    const float* inj_A  = (const float*)d_in[12];
    const float* inj_B  = (const float*)d_in[13];
    const float* act_w  = (const float*)d_in[14];
    const float* act_b  = (const float*)d_in[15];
    const float* loop_table = (const float*)d_in[16];

    char* p;
    if (ws_size >= WS_NEED) {
        p = (char*)d_ws;
    } else {
        void* sym = nullptr;
        hipGetSymbolAddress(&sym, HIP_SYMBOL(g_ws));
        p = (char*)sym;
    }

    float* h      = (float*)p;            p += (size_t)MR * DD * 4;      // 64 MiB
    unsigned short* he_bf = (unsigned short*)p; p += (size_t)MR * 2048 * 2; // 64
    unsigned short* xn_bf = (unsigned short*)p; p += (size_t)MR * DD * 2;   // 32
    unsigned short* q_bf  = (unsigned short*)p; p += (size_t)MR * DKK * 2;  // 32
    unsigned short* k_bf  = (unsigned short*)p; p += (size_t)MR * DKK * 2;  // 32
    unsigned short* v_bf  = (unsigned short*)p; p += (size_t)MR * DVV * 2;  // 64
    unsigned short* xg_bf = (unsigned short*)p; p += (size_t)MR * DVV * 2;  // 64
    float* lgbuf  = (float*)p;            p += (size_t)MR * DKK * 4;        // 64
    unsigned short* ob0   = (unsigned short*)p; p += (size_t)MR * DVV * 2;  // 64
    float* U      = (float*)p;            p += (size_t)NCH * 32 * DKH * DVH * 4; // 128
    float* dLe    = (float*)p;            p += (size_t)NCH * 32 * DKH * 4;
    unsigned short* WprojT = (unsigned short*)p; p += (size_t)NPROJ * DKK * 2;   // 14.7
    unsigned short* WoT    = (unsigned short*)p; p += (size_t)DD * DVV * 2;
    unsigned short* WinjT  = (unsigned short*)p; p += (size_t)DD * 2048 * 2;
    float* diagA = (float*)p;             p += DD * 4;
    float* tmp16 = (float*)p;             p += (size_t)MR * 16 * 4;
    float* cum   = (float*)p;             p += MR * 4;
    int*   halted = (int*)p;              p += MR * 4;
    // Aliases (lifetime-checked):
    float* g2 = lgbuf;              // lg consumed by c1; g2 written by Wo GEMM later
    unsigned short* Sbf = (unsigned short*)lgbuf;  // 64 MiB == lgbuf size exactly;
    // timeline: proj writes lg -> c1 reads lg -> c3 writes Sbf -> c4 reads Sbf
    // -> Wo GEMM writes g2 (same memory). No overlap of live ranges.
    float* h_out = (float*)d_out;

    hipMemcpyAsync(h, in_h, (size_t)MR * DD * 4, hipMemcpyDeviceToDevice, stream);
    hipMemsetAsync(h_out, 0, (size_t)MR * DD * 4, stream);
    hipMemsetAsync(cum, 0, MR * 4, stream);
    hipMemsetAsync(halted, 0, MR * 4, stream);

    // Weight prep
    k_transpose_bf16<<<dim3(16, 16), 256, 0, stream>>>(Wq,  WprojT,              DD, DKK);
    k_transpose_bf16<<<dim3(16, 16), 256, 0, stream>>>(Wk,  WprojT + 1024*1024,  DD, DKK);
    k_transpose_bf16<<<dim3(16, 16), 256, 0, stream>>>(Wgk, WprojT + 2048*1024,  DD, DKK);
    k_transpose_bf16<<<dim3(32, 16), 256, 0, stream>>>(Wv,  WprojT + 3072*1024,  DD, DVV);
    k_transpose_bf16<<<dim3(32, 16), 256, 0, stream>>>(Wg,  WprojT + (size_t)5120*1024, DD, DVV);
    k_transpose_bf16<<<dim3(16, 32), 256, 0, stream>>>(Wo,  WoT, DVV, DD);
    k_conv_injcomb<<<4096, 256, 0, stream>>>(inj_A, inj_B, WinjT, diagA);
    k_conv_e<<<MR * DD / 1024, 256, 0, stream>>>(in_e, he_bf);

    const float qscale = 0.08838834764831845f;   // 128^-0.5

    for (int t = 0; t < NLOOPS; ++t) {
        k_prep<<<MR, 256, 0, stream>>>(h, in_e, norm_w, loop_table + t * 128, he_bf, xn_bf);

        // fused 5-way projection (256^2 core, NT-store epilogue): 1792 blocks
        k_gemm_proj8<<<1792, 512, 131072, stream>>>(
            xn_bf, WprojT, q_bf, k_bf, lgbuf, v_bf, xg_bf, qscale);

        // chunked GLA scan
        k_c1<<<dim3(NCH, 16), 256, 0, stream>>>(lgbuf, q_bf, k_bf, dLe);
        k_c2<<<dim3(NCH, 32), 512, 4 * LCH * PADW * 2, stream>>>(
            q_bf, k_bf, v_bf, ob0, U);
        k_c3<<<1024, 256, 0, stream>>>(U, dLe, Sbf);
        k_c4<<<dim3(NCH, 32), 256, 2 * LCH * PADW * 2, stream>>>(q_bf, Sbf, ob0, xg_bf);

        // Wo projection: 64*4 = 256 blocks, K=2048 (KB=4096)
        k_gemm8_f32<0, 0, 4096><<<256, 512, 131072, stream>>>(
            ob0, WoT, g2, nullptr, nullptr, nullptr, DD);

        k_lora1<<<MR / 4, 256, 0, stream>>>(g2, lora_A + (size_t)t * DD * 16, tmp16);
        k_lora2<<<MR, 256, 0, stream>>>(g2, tmp16, lora_B + (size_t)t * 16 * DD);

        // h = [h|e] @ [injA|injB]^T + diagA*h + g2   (in place on h)
        k_gemm8_f32<1, 1, 4096><<<256, 512, 131072, stream>>>(
            he_bf, WinjT, h, g2, h, diagA, DD);

        k_act<<<MR, 256, 0, stream>>>(h, act_w, act_b, h_out, cum, halted);
    }

    k_final<<<MR, 256, 0, stream>>>(h_out, out_norm_w);
}

// Round 9
// 4172.976 us; speedup vs baseline: 1.1803x; 1.1803x over previous
//
#include <hip/hip_runtime.h>

// ---------------------------------------------------------------------------
// Problem constants (B=4, T=4096, D=1024, H=8, DK=1024, DV=2048, RANK=16,
// LOOPD=128, n_loops=4)
// ---------------------------------------------------------------------------
#define BB 4
#define TT 4096
#define DD 1024
#define HH 8
#define DKK 1024
#define DVV 2048
#define MR (BB*TT)          // 16384 rows
#define DKH 128
#define DVH 256
#define NLOOPS 4
#define LCH 128             // scan chunk length
#define NCH (TT/LCH)        // 32 chunks per batch
#define PADW 136            // LDS row stride (shorts) for scan kernels
#define NPROJ 7168          // q(1024) | k(1024) | lg(1024) | v(2048) | xg(2048)

// Total workspace need (bytes) — identical to rounds 3-6 (all passed).
// Sbf (64 MiB) aliases lgbuf (64 MiB): lg is consumed by c1 before c3 writes
// Sbf; c4 reads Sbf before the Wo GEMM overwrites the same memory as g2.
#define WS_NEED 662310912ull

// Static fallback workspace (module-load allocated; used when ws_size < WS_NEED)
__device__ __attribute__((aligned(256))) unsigned char g_ws[WS_NEED];

typedef __bf16 bf16x8 __attribute__((ext_vector_type(8)));
typedef float  f32x4  __attribute__((ext_vector_type(4)));

__device__ __forceinline__ unsigned short f2bfu(float f) {
    unsigned int u = __builtin_bit_cast(unsigned int, f);
    u += 0x7fffu + ((u >> 16) & 1u);
    return (unsigned short)(u >> 16);
}
__device__ __forceinline__ float bfu2f(unsigned short s) {
    unsigned int u = ((unsigned int)s) << 16;
    return __builtin_bit_cast(float, u);
}

__device__ __forceinline__ void gld_lds16(const void* g, void* l) {
    __builtin_amdgcn_global_load_lds(
        (__attribute__((address_space(1))) void*)const_cast<void*>(g),
        (__attribute__((address_space(3))) void*)l, 16, 0, 0);
}

// NOTE (r8 post-mortem): __builtin_nontemporal_store on the GEMM epilogue was
// REFUTED — FETCH unchanged, WRITE +44% (nt bypasses write-coalescing; 2B
// stores stop merging), downstream readers lose cache residency. Plain stores.

// ---------------------------------------------------------------------------
// Weight prep: fp32 [K][N] -> bf16 [N][K]  (B^T layout for the MFMA GEMM)
// ---------------------------------------------------------------------------
__global__ __launch_bounds__(256) void k_transpose_bf16(
    const float* __restrict__ in, unsigned short* __restrict__ out, int K, int N)
{
    __shared__ float tile[64][65];
    int k0 = blockIdx.y * 64, n0 = blockIdx.x * 64;
    int tx = threadIdx.x & 63, ty = threadIdx.x >> 6;
    #pragma unroll
    for (int r = 0; r < 64; r += 4)
        tile[ty + r][tx] = in[(size_t)(k0 + ty + r) * N + n0 + tx];
    __syncthreads();
    #pragma unroll
    for (int r = 0; r < 64; r += 4)
        out[(size_t)(n0 + ty + r) * K + k0 + tx] = f2bfu(tile[tx][ty + r]);
}

// e fp32 [MR][1024] -> bf16 into he[row][1024..2047]
__global__ __launch_bounds__(256) void k_conv_e(
    const float* __restrict__ e, unsigned short* __restrict__ he)
{
    size_t gid = (size_t)blockIdx.x * 256 + threadIdx.x;
    size_t b4 = gid * 4;
    size_t row = b4 >> 10; int col = (int)(b4 & 1023);
    float4 v = *(const float4*)&e[row * 1024 + col];
    *(ushort4*)&he[row * 2048 + 1024 + col] =
        make_ushort4(f2bfu(v.x), f2bfu(v.y), f2bfu(v.z), f2bfu(v.w));
}

// Combined injection weight: WinjT[n][0:1024]=injA[n][:] (diag zeroed,
// extracted), WinjT[n][1024:2048]=injB[n][:]
__global__ __launch_bounds__(256) void k_conv_injcomb(
    const float* __restrict__ injA, const float* __restrict__ injB,
    unsigned short* __restrict__ WinjT, float* __restrict__ diag)
{
    int idx = blockIdx.x * 256 + threadIdx.x;      // over 1024*1024
    int i = idx >> 10, j = idx & 1023;
    float va = injA[idx], vb = injB[idx];
    unsigned short ua;
    if (i == j) { diag[i] = va; ua = 0; }
    else        { ua = f2bfu(va); }
    WinjT[(size_t)i * 2048 + j] = ua;
    WinjT[(size_t)i * 2048 + 1024 + j] = f2bfu(vb);
}

// ---------------------------------------------------------------------------
// prep: h[:, :128] += loop_table[t]; xn = rmsnorm(h+e)*w -> bf16;
//       he[row][0:1024] = bf16(h)
// ---------------------------------------------------------------------------
__global__ __launch_bounds__(256) void k_prep(
    float* __restrict__ h, const float* __restrict__ e,
    const float* __restrict__ norm_w, const float* __restrict__ ltab,
    unsigned short* __restrict__ he, unsigned short* __restrict__ xn_bf)
{
    int row = blockIdx.x, tid = threadIdx.x;
    size_t base = (size_t)row * DD + tid * 4;
    float4 hv = *(float4*)&h[base];
    if (tid < 32) {
        float4 lv = *(const float4*)&ltab[tid * 4];
        hv.x += lv.x; hv.y += lv.y; hv.z += lv.z; hv.w += lv.w;
        *(float4*)&h[base] = hv;
    }
    float4 ev = *(const float4*)&e[base];
    float sx = hv.x + ev.x, sy = hv.y + ev.y, sz = hv.z + ev.z, sw = hv.w + ev.w;
    float partial = sx*sx + sy*sy + sz*sz + sw*sw;
    __shared__ float red[256];
    red[tid] = partial; __syncthreads();
    for (int st = 128; st > 0; st >>= 1) {
        if (tid < st) red[tid] += red[tid + st];
        __syncthreads();
    }
    float rms = rsqrtf(red[0] * (1.0f / DD) + 1e-6f);
    float4 wv = *(const float4*)&norm_w[tid * 4];
    *(ushort4*)&xn_bf[base] = make_ushort4(
        f2bfu(sx * rms * wv.x), f2bfu(sy * rms * wv.y),
        f2bfu(sz * rms * wv.z), f2bfu(sw * rms * wv.w));
    *(ushort4*)&he[(size_t)row * 2048 + tid * 4] =
        make_ushort4(f2bfu(hv.x), f2bfu(hv.y), f2bfu(hv.z), f2bfu(hv.w));
}

// ---------------------------------------------------------------------------
// Shared fragment/MFMA macros for the 256x256 8-wave GEMM core.
// Swizzle: byte a ^= ((a>>7)&7)<<4 within each 16K half (involution, 16B
// granule) — read-side XOR + pre-swizzled global source (linear LDS dest).
// ---------------------------------------------------------------------------
#define LD_AV(CB, MH) \
    _Pragma("unroll") \
    for (int i2 = 0; i2 < 4; ++i2) { \
        const char* rp = sm + (CB) + ((MH) * 16384) \
                       + ((wm * 64 + i2 * 16 + ln15) * 128); \
        av[i2][0] = *(const bf16x8*)(rp + xc0); \
        av[i2][1] = *(const bf16x8*)(rp + xc1); \
    }
#define LD_BV(CB, NH) \
    _Pragma("unroll") \
    for (int j2 = 0; j2 < 2; ++j2) { \
        const char* rp = sm + (CB) + 32768 + ((NH) * 16384) \
                       + ((wn * 32 + j2 * 16 + ln15) * 128); \
        bv[NH][j2][0] = *(const bf16x8*)(rp + xc0); \
        bv[NH][j2][1] = *(const bf16x8*)(rp + xc1); \
    }
#define MFMA_Q(MH, NH) \
    __builtin_amdgcn_s_setprio(1); \
    _Pragma("unroll") \
    for (int i2 = 0; i2 < 4; ++i2) \
        _Pragma("unroll") \
        for (int j2 = 0; j2 < 2; ++j2) { \
            acc[(MH)*4+i2][(NH)*2+j2] = __builtin_amdgcn_mfma_f32_16x16x32_bf16( \
                av[i2][0], bv[NH][j2][0], acc[(MH)*4+i2][(NH)*2+j2], 0, 0, 0); \
            acc[(MH)*4+i2][(NH)*2+j2] = __builtin_amdgcn_mfma_f32_16x16x32_bf16( \
                av[i2][1], bv[NH][j2][1], acc[(MH)*4+i2][(NH)*2+j2], 0, 0, 0); \
        } \
    __builtin_amdgcn_s_setprio(0);

// ---------------------------------------------------------------------------
// Single-tile 256x256 8-wave GEMM core, fragment-reuse + read-ahead.
// (Verified round-3/4 structure — epilogue strictly AFTER the loop.)
// Per K-tile:
//   P0: stage A-h0(next); vmcnt(4); bar; read av0+bv0+bv1 [16]; MFMA(0,0)
//   P1: stage B-h0(next);                                       MFMA(0,1)
//   P2: stage B-h1(next); vmcnt(6); bar; read av1         [8];  MFMA(1,1)
//   P3: stage A-h1(next);                                       MFMA(1,0)
// vmcnt induction (units of 2 loads): entering P0 = 8 outstanding
// [A0,B0,B1,A1](cur); +stage=10; vmcnt(4) drains A0,B0,B1(cur);
// P2: 8, vmcnt(6) drains A1(cur). Peel: 8 -> vmcnt(2) -> vmcnt(0).
// ---------------------------------------------------------------------------
template<int KB>   // K dimension in BYTES (= 2*K elements)
__device__ __forceinline__ void gemm8_core(
    const char* __restrict__ Ab, const char* __restrict__ Bb,
    int bm, int bn, char* sm, f32x4 (&acc)[8][4])
{
    constexpr int NKT = KB / 128;      // number of 64-element K-tiles
    const int tid = threadIdx.x;
    const int lane = tid & 63;
    const int wave = tid >> 6;
    const int wm = wave >> 2, wn = wave & 3;
    const int ln15 = lane & 15, q4 = lane >> 4;
    const int xorv = (ln15 & 7) << 4;
    const int xc0 = (q4 * 16) ^ xorv;
    const int xc1 = (64 + q4 * 16) ^ xorv;

    const int L0 = tid * 16;
    const int L1 = 8192 + tid * 16;
    const int lin0 = L0 ^ (((L0 >> 7) & 7) << 4);
    const int lin1 = L1 ^ (((L1 >> 7) & 7) << 4);
    const int sr0 = lin0 >> 7, sc0 = lin0 & 127;
    const int sr1 = lin1 >> 7, sc1 = lin1 & 127;

    bf16x8 av[4][2];
    bf16x8 bv[2][2][2];

    auto STAGE = [&](const char* gb, int row0, int kcol, int region) {
        gld_lds16(gb + (size_t)(row0 + sr0) * KB + (kcol + sc0), sm + region + L0);
        gld_lds16(gb + (size_t)(row0 + sr1) * KB + (kcol + sc1), sm + region + L1);
    };

    STAGE(Ab, bm,       0, 0);
    STAGE(Bb, bn,       0, 32768);
    STAGE(Bb, bn + 128, 0, 49152);
    STAGE(Ab, bm + 128, 0, 16384);

    #pragma unroll 2
    for (int kt = 0; kt < NKT - 1; ++kt) {
        const int cb = (kt & 1) << 16;
        const int sb = cb ^ 65536;
        const int kcol = (kt + 1) * 128;
        STAGE(Ab, bm, kcol, sb);
        asm volatile("s_waitcnt vmcnt(4)" ::: "memory");
        __builtin_amdgcn_s_barrier();
        LD_AV(cb, 0)
        LD_BV(cb, 0)
        LD_BV(cb, 1)
        MFMA_Q(0, 0)
        STAGE(Bb, bn, kcol, sb + 32768);
        MFMA_Q(0, 1)
        STAGE(Bb, bn + 128, kcol, sb + 49152);
        asm volatile("s_waitcnt vmcnt(6)" ::: "memory");
        __builtin_amdgcn_s_barrier();
        LD_AV(cb, 1)
        MFMA_Q(1, 1)
        STAGE(Ab, bm + 128, kcol, sb + 16384);
        MFMA_Q(1, 0)
    }
    {   // peeled last K-tile: drain 2 -> 0
        const int cb = ((NKT - 1) & 1) << 16;
        asm volatile("s_waitcnt vmcnt(2)" ::: "memory");
        __builtin_amdgcn_s_barrier();
        LD_AV(cb, 0)
        LD_BV(cb, 0)
        LD_BV(cb, 1)
        MFMA_Q(0, 0)
        MFMA_Q(0, 1)
        asm volatile("s_waitcnt vmcnt(0)" ::: "memory");
        __builtin_amdgcn_s_barrier();
        LD_AV(cb, 1)
        MFMA_Q(1, 1)
        MFMA_Q(1, 0)
    }
}

// ---------------------------------------------------------------------------
// Fused 5-way projection GEMM on the core (grid 1792, XCD swizzle).
// N-segments all 256-aligned: q[0,1024) k[1024,2048) lg[2048,3072)
// v[3072,5120) xg[5120,7168).  Plain direct stores (verified 295us config).
// ---------------------------------------------------------------------------
__global__ __launch_bounds__(512, 2) void k_gemm_proj8(
    const unsigned short* __restrict__ A, const unsigned short* __restrict__ Bt,
    unsigned short* __restrict__ qout, unsigned short* __restrict__ kout,
    float* __restrict__ lgout, unsigned short* __restrict__ vout,
    unsigned short* __restrict__ xgout, float qscale)
{
    extern __shared__ char sm[];
    // bijective XCD swizzle: nwg=1792, 1792/8=224
    int bid = blockIdx.x;
    int nb = (bid & 7) * 224 + (bid >> 3);
    int bm = (nb / 28) * 256, bn = (nb % 28) * 256;

    f32x4 acc[8][4];
    #pragma unroll
    for (int i = 0; i < 8; ++i)
        #pragma unroll
        for (int j = 0; j < 4; ++j) { f32x4 z = {0,0,0,0}; acc[i][j] = z; }

    gemm8_core<2048>((const char*)A, (const char*)Bt, bm, bn, sm, acc);

    const int tid = threadIdx.x, lane = tid & 63, wave = tid >> 6;
    const int wm = wave >> 2, wn = wave & 3;
    const int ln15 = lane & 15, q4 = lane >> 4;

    if (bn >= 2048 && bn < 3072) {
        int cb = bn - 2048;
        #pragma unroll
        for (int fm = 0; fm < 8; ++fm) {
            int mh = fm >> 2, i2 = fm & 3;
            int rowb = bm + mh * 128 + wm * 64 + i2 * 16 + q4 * 4;
            #pragma unroll
            for (int fn = 0; fn < 4; ++fn) {
                int nh = fn >> 1, j2 = fn & 1;
                int col = cb + nh * 128 + wn * 32 + j2 * 16 + ln15;
                #pragma unroll
                for (int r = 0; r < 4; ++r) {
                    float v = acc[fm][fn][r];
                    v = (fminf(v, 0.f) - log1pf(expf(-fabsf(v)))) * 0.0625f;
                    lgout[(size_t)(rowb + r) * 1024 + col] = v;
                }
            }
        }
    } else {
        unsigned short* obuf; int stride, cbc;
        float scale = 1.f;
        if (bn < 1024)      { obuf = qout;  stride = 1024; cbc = bn;        scale = qscale; }
        else if (bn < 2048) { obuf = kout;  stride = 1024; cbc = bn - 1024; }
        else if (bn < 5120) { obuf = vout;  stride = 2048; cbc = bn - 3072; }
        else                { obuf = xgout; stride = 2048; cbc = bn - 5120; }
        #pragma unroll
        for (int fm = 0; fm < 8; ++fm) {
            int mh = fm >> 2, i2 = fm & 3;
            int rowb = bm + mh * 128 + wm * 64 + i2 * 16 + q4 * 4;
            #pragma unroll
            for (int fn = 0; fn < 4; ++fn) {
                int nh = fn >> 1, j2 = fn & 1;
                int col = cbc + nh * 128 + wn * 32 + j2 * 16 + ln15;
                #pragma unroll
                for (int r = 0; r < 4; ++r)
                    obuf[(size_t)(rowb + r) * stride + col] =
                        f2bfu(acc[fm][fn][r] * scale);
            }
        }
    }
}

// fp32-output GEMM (Wo / injection) on the core.
// HASADD: += addend[oi]; HASDIAG: += hsrc[oi]*diag[col] (in-place-safe).
template<int HASADD, int HASDIAG, int KB>
__global__ __launch_bounds__(512, 2) void k_gemm8_f32(
    const unsigned short* __restrict__ A, const unsigned short* __restrict__ Bt,
    float* __restrict__ out, const float* __restrict__ addend,
    const float* __restrict__ hsrc, const float* __restrict__ diag, int N)
{
    extern __shared__ char sm[];
    int bid = blockIdx.x;
    int cpx = gridDim.x >> 3;                  // nwg % 8 == 0
    int nb = (bid & 7) * cpx + (bid >> 3);
    int nbn = N >> 8;
    int bm = (nb / nbn) * 256, bn = (nb % nbn) * 256;

    f32x4 acc[8][4];
    #pragma unroll
    for (int i = 0; i < 8; ++i)
        #pragma unroll
        for (int j = 0; j < 4; ++j) { f32x4 z = {0,0,0,0}; acc[i][j] = z; }

    gemm8_core<KB>((const char*)A, (const char*)Bt, bm, bn, sm, acc);

    const int tid = threadIdx.x, lane = tid & 63, wave = tid >> 6;
    const int wm = wave >> 2, wn = wave & 3;
    const int ln15 = lane & 15, q4 = lane >> 4;

    #pragma unroll
    for (int fm = 0; fm < 8; ++fm) {
        int mh = fm >> 2, i2 = fm & 3;
        int rowb = bm + mh * 128 + wm * 64 + i2 * 16 + q4 * 4;
        #pragma unroll
        for (int fn = 0; fn < 4; ++fn) {
            int nh = fn >> 1, j2 = fn & 1;
            int col = bn + nh * 128 + wn * 32 + j2 * 16 + ln15;
            float dg = 0.f;
            if (HASDIAG) dg = diag[col];
            #pragma unroll
            for (int r = 0; r < 4; ++r) {
                size_t oi = (size_t)(rowb + r) * N + col;
                float v = acc[fm][fn][r];
                if (HASDIAG) v += hsrc[oi] * dg;
                if (HASADD)  v += addend[oi];
                out[oi] = v;
            }
        }
    }
}

#undef LD_AV
#undef LD_BV
#undef MFMA_Q

// ---------------------------------------------------------------------------
// Chunked GLA scan, phase C1: per (chunk, bh), per channel i:
//   c_t = cumsum(lg); q <- q*exp(c_t); k <- k*exp(-c_t); dLe = exp(c_L)
// 256 threads = 2 bh per block.
// ---------------------------------------------------------------------------
__global__ __launch_bounds__(256) void k_c1(
    const float* __restrict__ lg, unsigned short* __restrict__ q,
    unsigned short* __restrict__ kk, float* __restrict__ dLe)
{
    int chunk = blockIdx.x;
    int bh = blockIdx.y * 2 + (threadIdx.x >> 7);
    int b = bh >> 3, h = bh & 7;
    int i = threadIdx.x & 127;
    size_t r0 = (size_t)b * TT + (size_t)chunk * LCH;
    float c = 0.f, e = 1.f;
    for (int t = 0; t < LCH; ++t) {
        size_t off = (r0 + t) * DKK + h * DKH + i;
        c += lg[off];
        e = __expf(c);
        float ei = __expf(-c);
        q[off] = f2bfu(bfu2f(q[off]) * e);
        kk[off] = f2bfu(bfu2f(kk[off]) * ei);
    }
    dLe[((size_t)chunk * 32 + bh) * DKH + i] = e;
}

// ---------------------------------------------------------------------------
// C2: per (chunk, bh): P = causal(Q~ K~^T);  O_intra = P V -> ob (bf16);
//     U = K~^T V -> fp32.  Dynamic LDS: 4 * 128*PADW shorts = 139264 B.
// 512 threads (8 waves), 2(wm) x 4(wn) wave grid over each 128-wide panel.
// ---------------------------------------------------------------------------
__global__ __launch_bounds__(512, 1) void k_c2(
    const unsigned short* __restrict__ q, const unsigned short* __restrict__ kk,
    const unsigned short* __restrict__ v, unsigned short* __restrict__ ob,
    float* __restrict__ U)
{
    extern __shared__ unsigned short smd[];
    unsigned short* lQ  = smd;                 // [t][i], later P [t][s]
    unsigned short* lK  = smd + LCH * PADW;    // [s][i]
    unsigned short* lKT = smd + 2 * LCH * PADW;// [i][s]
    unsigned short* lVT = smd + 3 * LCH * PADW;// [j][s] (one 128-wide j panel)

    int chunk = blockIdx.x, bh = blockIdx.y;
    int b = bh >> 3, h = bh & 7;
    int tid = threadIdx.x, lane = tid & 63, wave = tid >> 6;
    int wm = wave >> 2, wn = wave & 3;
    int quad = lane >> 4, mr = lane & 15;
    size_t r0 = (size_t)b * TT + (size_t)chunk * LCH;

    #pragma unroll
    for (int ps = 0; ps < 4; ++ps) {
        int idx = ps * 512 + tid;
        int row = idx >> 4, c8 = (idx & 15) * 8;
        size_t g = (r0 + row) * DKK + h * DKH + c8;
        *(int4*)&lQ[row * PADW + c8] = *(const int4*)&q[g];
        union { int4 w; unsigned short u[8]; } tmp;
        tmp.w = *(const int4*)&kk[g];
        *(int4*)&lK[row * PADW + c8] = tmp.w;
        #pragma unroll
        for (int u2 = 0; u2 < 8; ++u2)
            lKT[(c8 + u2) * PADW + row] = tmp.u[u2];
    }
    __syncthreads();

    f32x4 pa[4][2];
    #pragma unroll
    for (int i = 0; i < 4; ++i)
        #pragma unroll
        for (int j = 0; j < 2; ++j) { f32x4 z = {0,0,0,0}; pa[i][j] = z; }
    for (int k0 = 0; k0 < DKH; k0 += 32) {
        bf16x8 av[4], bvv[2];
        #pragma unroll
        for (int t2 = 0; t2 < 4; ++t2)
            av[t2] = *(const bf16x8*)&lQ[(wm * 64 + t2 * 16 + mr) * PADW + k0 + quad * 8];
        #pragma unroll
        for (int tn = 0; tn < 2; ++tn)
            bvv[tn] = *(const bf16x8*)&lK[(wn * 32 + tn * 16 + mr) * PADW + k0 + quad * 8];
        #pragma unroll
        for (int tm = 0; tm < 4; ++tm)
            #pragma unroll
            for (int tn = 0; tn < 2; ++tn)
                pa[tm][tn] = __builtin_amdgcn_mfma_f32_16x16x32_bf16(
                    av[tm], bvv[tn], pa[tm][tn], 0, 0, 0);
    }
    __syncthreads();

    #pragma unroll
    for (int tm = 0; tm < 4; ++tm)
        #pragma unroll
        for (int tn = 0; tn < 2; ++tn)
            #pragma unroll
            for (int r = 0; r < 4; ++r) {
                int trow = wm * 64 + tm * 16 + quad * 4 + r;
                int scol = wn * 32 + tn * 16 + mr;
                float pv = (trow >= scol) ? pa[tm][tn][r] : 0.f;
                lQ[trow * PADW + scol] = f2bfu(pv);
            }
    #pragma unroll
    for (int ps = 0; ps < 4; ++ps) {
        int idx = ps * 512 + tid;
        int s = idx >> 4, j8 = (idx & 15) * 8;
        size_t g = (r0 + s) * DVV + h * DVH + j8;   // panel 0
        union { int4 w; unsigned short u[8]; } tmp;
        tmp.w = *(const int4*)&v[g];
        #pragma unroll
        for (int u2 = 0; u2 < 8; ++u2)
            lVT[(j8 + u2) * PADW + s] = tmp.u[u2];
    }
    __syncthreads();

    #pragma unroll 1
    for (int panel = 0; panel < 2; ++panel) {
        f32x4 oa[4][2], ua[4][2];
        #pragma unroll
        for (int i = 0; i < 4; ++i)
            #pragma unroll
            for (int j = 0; j < 2; ++j) { f32x4 z = {0,0,0,0}; oa[i][j] = z; ua[i][j] = z; }
        for (int k0 = 0; k0 < LCH; k0 += 32) {
            bf16x8 pv[4], kt[4], vb[2];
            #pragma unroll
            for (int t2 = 0; t2 < 4; ++t2) {
                pv[t2] = *(const bf16x8*)&lQ [(wm * 64 + t2 * 16 + mr) * PADW + k0 + quad * 8];
                kt[t2] = *(const bf16x8*)&lKT[(wm * 64 + t2 * 16 + mr) * PADW + k0 + quad * 8];
            }
            #pragma unroll
            for (int tn = 0; tn < 2; ++tn)
                vb[tn] = *(const bf16x8*)&lVT[(wn * 32 + tn * 16 + mr) * PADW + k0 + quad * 8];
            #pragma unroll
            for (int tm = 0; tm < 4; ++tm)
                #pragma unroll
                for (int tn = 0; tn < 2; ++tn) {
                    oa[tm][tn] = __builtin_amdgcn_mfma_f32_16x16x32_bf16(
                        pv[tm], vb[tn], oa[tm][tn], 0, 0, 0);
                    ua[tm][tn] = __builtin_amdgcn_mfma_f32_16x16x32_bf16(
                        kt[tm], vb[tn], ua[tm][tn], 0, 0, 0);
                }
        }
        #pragma unroll
        for (int tm = 0; tm < 4; ++tm)
            #pragma unroll
            for (int tn = 0; tn < 2; ++tn)
                #pragma unroll
                for (int r = 0; r < 4; ++r) {
                    int m_ = wm * 64 + tm * 16 + quad * 4 + r;
                    int j_ = panel * 128 + wn * 32 + tn * 16 + mr;
                    ob[(r0 + m_) * DVV + h * DVH + j_] = f2bfu(oa[tm][tn][r]);
                    U[(((size_t)chunk * 32 + bh) * DKH + m_) * DVH + j_] = ua[tm][tn][r];
                }
        __syncthreads();
        if (panel == 0) {
            #pragma unroll
            for (int ps = 0; ps < 4; ++ps) {
                int idx = ps * 512 + tid;
                int s = idx >> 4, j8 = (idx & 15) * 8;
                size_t g = (r0 + s) * DVV + h * DVH + 128 + j8;   // panel 1
                union { int4 w; unsigned short u[8]; } tmp;
                tmp.w = *(const int4*)&v[g];
                #pragma unroll
                for (int u2 = 0; u2 < 8; ++u2)
                    lVT[(j8 + u2) * PADW + s] = tmp.u[u2];
            }
            __syncthreads();
        }
    }
}

// ---------------------------------------------------------------------------
// C3: sequential inter-chunk combine.  Reads U (fp32, from c2); writes the
// PRE-update state S_c as bf16 into Sbf (c4 converts to bf16 for MFMA anyway
// — same rounding, applied earlier; halves c3-write + c4-read traffic).
// Sbf aliases lgbuf (lg already consumed by c1; Wo GEMM overwrites later).
// ---------------------------------------------------------------------------
__global__ __launch_bounds__(256) void k_c3(
    const float* __restrict__ U, const float* __restrict__ dLe,
    unsigned short* __restrict__ Sbf)
{
    int gid = blockIdx.x * 256 + threadIdx.x;   // 262144 threads
    int bh = gid >> 13;
    int rem = gid & 8191;
    int i = rem >> 6, j4 = rem & 63;
    float4 S = make_float4(0.f, 0.f, 0.f, 0.f);
    for (int c = 0; c < NCH; ++c) {
        size_t off = (((size_t)c * 32 + bh) * DKH + i) * DVH + j4 * 4;
        float4 u = *(const float4*)&U[off];
        *(ushort4*)&Sbf[off] = make_ushort4(
            f2bfu(S.x), f2bfu(S.y), f2bfu(S.z), f2bfu(S.w));
        float d = dLe[((size_t)c * 32 + bh) * DKH + i];
        S.x = d * (S.x + u.x); S.y = d * (S.y + u.y);
        S.z = d * (S.z + u.z); S.w = d * (S.w + u.w);
    }
}

// ---------------------------------------------------------------------------
// C4: ob = (ob_intra + Q~ @ S_c) * silu(xg)   (gate fused), S in bf16.
// Dynamic LDS: 2 * 128*PADW shorts = 69632 B.
// ---------------------------------------------------------------------------
__global__ __launch_bounds__(256, 1) void k_c4(
    const unsigned short* __restrict__ q, const unsigned short* __restrict__ Sbf,
    unsigned short* __restrict__ ob, const unsigned short* __restrict__ xg)
{
    extern __shared__ unsigned short smd[];
    unsigned short* lQ  = smd;               // [t][i]
    unsigned short* lST = smd + LCH * PADW;  // [j][i]

    int chunk = blockIdx.x, bh = blockIdx.y;
    int b = bh >> 3, h = bh & 7;
    int tid = threadIdx.x, lane = tid & 63, wave = tid >> 6;
    int wm = wave >> 1, wn = wave & 1;
    int quad = lane >> 4, mr = lane & 15;
    size_t r0 = (size_t)b * TT + (size_t)chunk * LCH;
    size_t sbase = ((size_t)chunk * 32 + bh) * DKH * DVH;

    #pragma unroll
    for (int ps = 0; ps < 8; ++ps) {
        int idx = ps * 256 + tid;
        int row = idx >> 4, c8 = (idx & 15) * 8;
        size_t g = (r0 + row) * DKK + h * DKH + c8;
        *(int4*)&lQ[row * PADW + c8] = *(const int4*)&q[g];
    }

    #pragma unroll 1
    for (int panel = 0; panel < 2; ++panel) {
        __syncthreads();
        #pragma unroll
        for (int ps = 0; ps < 8; ++ps) {
            int idx = ps * 256 + tid;
            int i = idx >> 4, j8 = (idx & 15) * 8;
            union { int4 w; unsigned short u[8]; } t8;
            t8.w = *(const int4*)&Sbf[sbase + (size_t)i * DVH + panel * 128 + j8];
            #pragma unroll
            for (int u2 = 0; u2 < 8; ++u2)
                lST[(j8 + u2) * PADW + i] = t8.u[u2];
        }
        __syncthreads();

        f32x4 oa[4][4];
        #pragma unroll
        for (int i = 0; i < 4; ++i)
            #pragma unroll
            for (int j = 0; j < 4; ++j) { f32x4 z = {0,0,0,0}; oa[i][j] = z; }
        for (int k0 = 0; k0 < DKH; k0 += 32) {
            bf16x8 av[4], bvv[4];
            #pragma unroll
            for (int t2 = 0; t2 < 4; ++t2) {
                av[t2] = *(const bf16x8*)&lQ [(wm * 64 + t2 * 16 + mr) * PADW + k0 + quad * 8];
                bvv[t2] = *(const bf16x8*)&lST[(wn * 64 + t2 * 16 + mr) * PADW + k0 + quad * 8];
            }
            #pragma unroll
            for (int tm = 0; tm < 4; ++tm)
                #pragma unroll
                for (int tn = 0; tn < 4; ++tn)
                    oa[tm][tn] = __builtin_amdgcn_mfma_f32_16x16x32_bf16(
                        av[tm], bvv[tn], oa[tm][tn], 0, 0, 0);
        }
        #pragma unroll
        for (int tm = 0; tm < 4; ++tm)
            #pragma unroll
            for (int tn = 0; tn < 4; ++tn)
                #pragma unroll
                for (int r = 0; r < 4; ++r) {
                    int t_ = wm * 64 + tm * 16 + quad * 4 + r;
                    int j_ = panel * 128 + wn * 64 + tn * 16 + mr;
                    size_t oi = (r0 + t_) * DVV + h * DVH + j_;
                    float ov = bfu2f(ob[oi]) + oa[tm][tn][r];
                    float xf = bfu2f(xg[oi]);
                    ob[oi] = f2bfu(ov * xf / (1.f + expf(-xf)));
                }
    }
}

// ---------------------------------------------------------------------------
// LoRA rank-16, fp32
// ---------------------------------------------------------------------------
__global__ __launch_bounds__(256) void k_lora1(
    const float* __restrict__ G, const float* __restrict__ A, float* __restrict__ tmp)
{
    int row = blockIdx.x * 4 + (threadIdx.x >> 6);
    int lane = threadIdx.x & 63;
    float acc[16];
    #pragma unroll
    for (int r = 0; r < 16; ++r) acc[r] = 0.f;
    const float* grow = G + (size_t)row * DD;
    for (int k2 = lane; k2 < DD; k2 += 64) {
        float g = grow[k2];
        const float4* ar = (const float4*)(A + k2 * 16);
        float4 a0 = ar[0], a1 = ar[1], a2 = ar[2], a3 = ar[3];
        acc[0] = fmaf(g, a0.x, acc[0]);  acc[1] = fmaf(g, a0.y, acc[1]);
        acc[2] = fmaf(g, a0.z, acc[2]);  acc[3] = fmaf(g, a0.w, acc[3]);
        acc[4] = fmaf(g, a1.x, acc[4]);  acc[5] = fmaf(g, a1.y, acc[5]);
        acc[6] = fmaf(g, a1.z, acc[6]);  acc[7] = fmaf(g, a1.w, acc[7]);
        acc[8] = fmaf(g, a2.x, acc[8]);  acc[9] = fmaf(g, a2.y, acc[9]);
        acc[10] = fmaf(g, a2.z, acc[10]); acc[11] = fmaf(g, a2.w, acc[11]);
        acc[12] = fmaf(g, a3.x, acc[12]); acc[13] = fmaf(g, a3.y, acc[13]);
        acc[14] = fmaf(g, a3.z, acc[14]); acc[15] = fmaf(g, a3.w, acc[15]);
    }
    #pragma unroll
    for (int off = 32; off >= 1; off >>= 1)
        #pragma unroll
        for (int r = 0; r < 16; ++r) acc[r] += __shfl_xor(acc[r], off);
    if (lane == 0) {
        #pragma unroll
        for (int r = 0; r < 16; ++r) tmp[(size_t)row * 16 + r] = acc[r];
    }
}

__global__ __launch_bounds__(256) void k_lora2(
    float* __restrict__ G, const float* __restrict__ tmp, const float* __restrict__ Bm)
{
    int row = blockIdx.x, tid = threadIdx.x;
    __shared__ float t16[16];
    if (tid < 16) t16[tid] = tmp[(size_t)row * 16 + tid];
    __syncthreads();
    size_t base = (size_t)row * DD + tid * 4;
    float4 acc = *(float4*)&G[base];
    #pragma unroll
    for (int r = 0; r < 16; ++r) {
        float tv = t16[r];
        float4 bv = *(const float4*)&Bm[r * DD + tid * 4];
        acc.x = fmaf(tv, bv.x, acc.x); acc.y = fmaf(tv, bv.y, acc.y);
        acc.z = fmaf(tv, bv.z, acc.z); acc.w = fmaf(tv, bv.w, acc.w);
    }
    *(float4*)&G[base] = acc;
}

// ---------------------------------------------------------------------------
// ACT halting (race-free via LDS staging)
// ---------------------------------------------------------------------------
__global__ __launch_bounds__(256) void k_act(
    const float* __restrict__ h, const float* __restrict__ act_w,
    const float* __restrict__ act_b, float* __restrict__ out,
    float* __restrict__ cum, int* __restrict__ halted)
{
    int row = blockIdx.x, tid = threadIdx.x;
    size_t base = (size_t)row * DD + tid * 4;
    float4 hv = *(const float4*)&h[base];
    float4 wv = *(const float4*)&act_w[tid * 4];
    float partial = hv.x*wv.x + hv.y*wv.y + hv.z*wv.z + hv.w*wv.w;
    __shared__ float red[256];
    __shared__ float s_cm;
    __shared__ int s_hl;
    if (tid == 0) { s_cm = cum[row]; s_hl = halted[row]; }
    red[tid] = partial; __syncthreads();
    for (int st = 128; st > 0; st >>= 1) {
        if (tid < st) red[tid] += red[tid + st];
        __syncthreads();
    }
    float p = 1.f / (1.f + expf(-(red[0] + act_b[0])));
    float cm = s_cm;
    int hl = s_hl;
    float p_eff = hl ? 0.f : p;
    float ncum = cm + p_eff;
    int newly = (!hl) && (ncum >= 0.99f);
    float w = newly ? (1.f - cm) : p_eff;
    float4 ho = *(float4*)&out[base];
    ho.x += w * hv.x; ho.y += w * hv.y; ho.z += w * hv.z; ho.w += w * hv.w;
    *(float4*)&out[base] = ho;
    if (tid == 0) { cum[row] = ncum; halted[row] = hl | newly; }
}

__global__ __launch_bounds__(256) void k_final(
    float* __restrict__ io, const float* __restrict__ w)
{
    int row = blockIdx.x, tid = threadIdx.x;
    size_t base = (size_t)row * DD + tid * 4;
    float4 hv = *(const float4*)&io[base];
    float partial = hv.x*hv.x + hv.y*hv.y + hv.z*hv.z + hv.w*hv.w;
    __shared__ float red[256];
    red[tid] = partial; __syncthreads();
    for (int st = 128; st > 0; st >>= 1) {
        if (tid < st) red[tid] += red[tid + st];
        __syncthreads();
    }
    float rms = rsqrtf(red[0] * (1.0f / DD) + 1e-6f);
    float4 wv = *(const float4*)&w[tid * 4];
    float4 o = make_float4(hv.x*rms*wv.x, hv.y*rms*wv.y, hv.z*rms*wv.z, hv.w*rms*wv.w);
    *(float4*)&io[base] = o;
}

// ---------------------------------------------------------------------------
extern "C" void kernel_launch(void* const* d_in, const int* in_sizes, int n_in,
                              void* d_out, int out_size, void* d_ws, size_t ws_size,
                              hipStream_t stream)
{
    const float* in_h       = (const float*)d_in[0];
    const float* in_e       = (const float*)d_in[1];
    const float* norm_w     = (const float*)d_in[2];
    const float* out_norm_w = (const float*)d_in[3];
    const float* Wq   = (const float*)d_in[4];
    const float* Wk   = (const float*)d_in[5];
    const float* Wv   = (const float*)d_in[6];
    const float* Wgk  = (const float*)d_in[7];
    const float* Wg   = (const float*)d_in[8];
    const float* Wo   = (const float*)d_in[9];
    const float* lora_A = (const float*)d_in[10];
    const float* lora_B = (const float*)d_in[11];
    const float* inj_A  = (const float*)d_in[12];
    const float* inj_B  = (const float*)d_in[13];
    const float* act_w  = (const float*)d_in[14];
    const float* act_b  = (const float*)d_in[15];
    const float* loop_table = (const float*)d_in[16];

    char* p;
    if (ws_size >= WS_NEED) {
        p = (char*)d_ws;
    } else {
        void* sym = nullptr;
        hipGetSymbolAddress(&sym, HIP_SYMBOL(g_ws));
        p = (char*)sym;
    }

    float* h      = (float*)p;            p += (size_t)MR * DD * 4;      // 64 MiB
    unsigned short* he_bf = (unsigned short*)p; p += (size_t)MR * 2048 * 2; // 64
    unsigned short* xn_bf = (unsigned short*)p; p += (size_t)MR * DD * 2;   // 32
    unsigned short* q_bf  = (unsigned short*)p; p += (size_t)MR * DKK * 2;  // 32
    unsigned short* k_bf  = (unsigned short*)p; p += (size_t)MR * DKK * 2;  // 32
    unsigned short* v_bf  = (unsigned short*)p; p += (size_t)MR * DVV * 2;  // 64
    unsigned short* xg_bf = (unsigned short*)p; p += (size_t)MR * DVV * 2;  // 64
    float* lgbuf  = (float*)p;            p += (size_t)MR * DKK * 4;        // 64
    unsigned short* ob0   = (unsigned short*)p; p += (size_t)MR * DVV * 2;  // 64
    float* U      = (float*)p;            p += (size_t)NCH * 32 * DKH * DVH * 4; // 128
    float* dLe    = (float*)p;            p += (size_t)NCH * 32 * DKH * 4;
    unsigned short* WprojT = (unsigned short*)p; p += (size_t)NPROJ * DKK * 2;   // 14.7
    unsigned short* WoT    = (unsigned short*)p; p += (size_t)DD * DVV * 2;
    unsigned short* WinjT  = (unsigned short*)p; p += (size_t)DD * 2048 * 2;
    float* diagA = (float*)p;             p += DD * 4;
    float* tmp16 = (float*)p;             p += (size_t)MR * 16 * 4;
    float* cum   = (float*)p;             p += MR * 4;
    int*   halted = (int*)p;              p += MR * 4;
    // Aliases (lifetime-checked):
    float* g2 = lgbuf;              // lg consumed by c1; g2 written by Wo GEMM later
    unsigned short* Sbf = (unsigned short*)lgbuf;  // 64 MiB == lgbuf size exactly;
    // timeline: proj writes lg -> c1 reads lg -> c3 writes Sbf -> c4 reads Sbf
    // -> Wo GEMM writes g2 (same memory). No overlap of live ranges.
    float* h_out = (float*)d_out;

    hipMemcpyAsync(h, in_h, (size_t)MR * DD * 4, hipMemcpyDeviceToDevice, stream);
    hipMemsetAsync(h_out, 0, (size_t)MR * DD * 4, stream);
    hipMemsetAsync(cum, 0, MR * 4, stream);
    hipMemsetAsync(halted, 0, MR * 4, stream);

    // Weight prep
    k_transpose_bf16<<<dim3(16, 16), 256, 0, stream>>>(Wq,  WprojT,              DD, DKK);
    k_transpose_bf16<<<dim3(16, 16), 256, 0, stream>>>(Wk,  WprojT + 1024*1024,  DD, DKK);
    k_transpose_bf16<<<dim3(16, 16), 256, 0, stream>>>(Wgk, WprojT + 2048*1024,  DD, DKK);
    k_transpose_bf16<<<dim3(32, 16), 256, 0, stream>>>(Wv,  WprojT + 3072*1024,  DD, DVV);
    k_transpose_bf16<<<dim3(32, 16), 256, 0, stream>>>(Wg,  WprojT + (size_t)5120*1024, DD, DVV);
    k_transpose_bf16<<<dim3(16, 32), 256, 0, stream>>>(Wo,  WoT, DVV, DD);
    k_conv_injcomb<<<4096, 256, 0, stream>>>(inj_A, inj_B, WinjT, diagA);
    k_conv_e<<<MR * DD / 1024, 256, 0, stream>>>(in_e, he_bf);

    const float qscale = 0.08838834764831845f;   // 128^-0.5

    for (int t = 0; t < NLOOPS; ++t) {
        k_prep<<<MR, 256, 0, stream>>>(h, in_e, norm_w, loop_table + t * 128, he_bf, xn_bf);

        // fused 5-way projection (256^2 core, direct-store epilogue): 1792 blocks
        k_gemm_proj8<<<1792, 512, 131072, stream>>>(
            xn_bf, WprojT, q_bf, k_bf, lgbuf, v_bf, xg_bf, qscale);

        // chunked GLA scan
        k_c1<<<dim3(NCH, 16), 256, 0, stream>>>(lgbuf, q_bf, k_bf, dLe);
        k_c2<<<dim3(NCH, 32), 512, 4 * LCH * PADW * 2, stream>>>(
            q_bf, k_bf, v_bf, ob0, U);
        k_c3<<<1024, 256, 0, stream>>>(U, dLe, Sbf);
        k_c4<<<dim3(NCH, 32), 256, 2 * LCH * PADW * 2, stream>>>(q_bf, Sbf, ob0, xg_bf);

        // Wo projection: 64*4 = 256 blocks, K=2048 (KB=4096)
        k_gemm8_f32<0, 0, 4096><<<256, 512, 131072, stream>>>(
            ob0, WoT, g2, nullptr, nullptr, nullptr, DD);

        k_lora1<<<MR / 4, 256, 0, stream>>>(g2, lora_A + (size_t)t * DD * 16, tmp16);
        k_lora2<<<MR, 256, 0, stream>>>(g2, tmp16, lora_B + (size_t)t * 16 * DD);

        // h = [h|e] @ [injA|injB]^T + diagA*h + g2   (in place on h)
        k_gemm8_f32<1, 1, 4096><<<256, 512, 131072, stream>>>(
            he_bf, WinjT, h, g2, h, diagA, DD);

        k_act<<<MR, 256, 0, stream>>>(h, act_w, act_b, h_out, cum, halted);
    }

    k_final<<<MR, 256, 0, stream>>>(h_out, out_norm_w);
}